// Round 8
// baseline (66.954 us; speedup 1.0000x reference)
//
#include <hip/hip_runtime.h>

typedef __bf16 bf16x8 __attribute__((ext_vector_type(8)));
typedef __bf16 bf16x4 __attribute__((ext_vector_type(4)));
typedef float f32x16 __attribute__((ext_vector_type(16)));
typedef float f32x4 __attribute__((ext_vector_type(4)));

constexpr int S = 128, R = 256, CM = 256, C = 32, CZ = 128;

#define MFMA __builtin_amdgcn_mfma_f32_32x32x16_bf16

__device__ __forceinline__ bf16x4 cvt4(float a, float b, float c, float d) {
    bf16x4 r;
    r[0] = (__bf16)a; r[1] = (__bf16)b; r[2] = (__bf16)c; r[3] = (__bf16)d;
    return r;
}

// K0a: fragment-packed out_proj. k = e*32+c, WTf[((k>>3)*128+cz)*8 + (k&7)] = W[(c*32+e)*128+cz]
__global__ __launch_bounds__(256) void k_wt(const float* __restrict__ W,
                                            __bf16* __restrict__ WTf) {
    int g = blockIdx.x * 256 + threadIdx.x;
    int cz = g & 127;
    int k = g >> 7;
    int e = k >> 5, c = k & 31;
    float v = W[(size_t)(c * 32 + e) * 128 + cz];
    WTf[((size_t)(k >> 3) * 128 + cz) * 8 + (k & 7)] = (__bf16)v;
}

// K0b: WLRT[c][m], c<32 -> left[m][c], else right[m][c-32]
__global__ __launch_bounds__(256) void k_wlr(const float* __restrict__ Lp,
                                             const float* __restrict__ Rp,
                                             __bf16* __restrict__ WLRT) {
    int c = blockIdx.x;
    int m = threadIdx.x;
    const float* src = (c < 32) ? Lp : Rp;
    WLRT[(size_t)c * 256 + m] = (__bf16)src[(size_t)m * 32 + (c & 31)];
}

// K1: block (r, s-half=64 rows). 512 thr / 8 waves = (ksh x sd x mi); K(m)-split
// halves + 2-way LDS reduction. Writes fragment-packed aTf/bTf[r][ks][khf][c][8s].
__global__ __launch_bounds__(512) void k_proj(const float* __restrict__ msa,
                                              const __bf16* __restrict__ WLRT,
                                              __bf16* __restrict__ aTf,
                                              __bf16* __restrict__ bTf) {
    __shared__ __align__(16) __bf16 As[64 * 256];       // 32 KB
    __shared__ __align__(16) char Pp[4 * 4096];         // 16 KB partials
    const int r = blockIdx.x;
    const int sh = blockIdx.y;
    const int t = threadIdx.x;

#pragma unroll
    for (int it = 0; it < 8; ++it) {
        int idx = it * 512 + t;
        int row = idx >> 6;            // 0..63
        int cg = idx & 63;
        float4 v = *(const float4*)&msa[((size_t)(sh * 64 + row) * R + r) * CM + cg * 4];
        bf16x4 h = cvt4(v.x, v.y, v.z, v.w);
        int P = (cg >> 1) ^ (row & 15);
        *(bf16x4*)((char*)As + row * 512 + P * 16 + (cg & 1) * 8) = h;
    }
    __syncthreads();

    const int w = t >> 6;
    const int l = t & 63;
    const int l31 = t & 31;
    const int kh = (t >> 5) & 1;
    const int ksh = w >> 2;            // m-half
    const int sd = (w >> 1) & 1;       // 0 = left, 1 = right
    const int mi = w & 1;              // 32-row group within the 64-row half

    f32x16 acc;
#pragma unroll
    for (int q = 0; q < 16; ++q) acc[q] = 0.f;

    const bf16x8* wb = (const bf16x8*)&WLRT[(size_t)(sd * 32 + l31) * 256 + 8 * kh];
    const int srow = mi * 32 + l31;
    const char* arow = (const char*)As + srow * 512;

    __builtin_amdgcn_s_setprio(1);
#pragma unroll
    for (int j = 0; j < 8; ++j) {
        int ks = ksh * 8 + j;
        int P = (2 * ks + kh) ^ (srow & 15);
        bf16x8 af = *(const bf16x8*)(arow + P * 16);
        acc = MFMA(af, wb[2 * ks], acc, 0, 0, 0);
    }
    __builtin_amdgcn_s_setprio(0);

    char* pbase = Pp + (size_t)(sd * 2 + mi) * 4096;
    if (ksh == 1) {
#pragma unroll
        for (int pc = 0; pc < 4; ++pc) {
            f32x4 v;
            v[0] = acc[4 * pc + 0]; v[1] = acc[4 * pc + 1];
            v[2] = acc[4 * pc + 2]; v[3] = acc[4 * pc + 3];
            *(f32x4*)(pbase + ((pc * 64) + l) * 16) = v;
        }
    }
    __syncthreads();
    if (ksh == 0) {
#pragma unroll
        for (int pc = 0; pc < 4; ++pc) {
            f32x4 v = *(const f32x4*)(pbase + ((pc * 64) + l) * 16);
            acc[4 * pc + 0] += v[0]; acc[4 * pc + 1] += v[1];
            acc[4 * pc + 2] += v[2]; acc[4 * pc + 3] += v[3];
        }
        __bf16* dst = sd ? bTf : aTf;
        const int wg = sh * 2 + mi;
#pragma unroll
        for (int q = 0; q < 4; ++q) {
            size_t base = (size_t)r * 4096 + (size_t)(2 * wg + (q >> 1)) * 512 +
                          (size_t)(q & 1) * 256 + (size_t)l31 * 8 + 4 * kh;
            *(bf16x4*)&dst[base] = cvt4(acc[4 * q + 0], acc[4 * q + 1],
                                        acc[4 * q + 2], acc[4 * q + 3]);
        }
    }
}

// K2: 64 pairs (8r x 8t), 1024 threads / 16 waves, 128 KB LDS, 4 waves/SIMD.
// Phase A: wave (rg=w>>2, tg=w&3) -> 2r x 2t sub-tile (acc 2x2).
// Phase B: wave (kq=w>>2, mt=(w>>1)&1, ng=w&1): 1 M-tile x 2 cz-slices over a
// K-quarter (1 G-read + 2 W-loads -> 2 MFMA); 4-way K reduction via dead G LDS.
__global__ __launch_bounds__(1024, 4) void k_main(const __bf16* __restrict__ aTf,
                                                  const __bf16* __restrict__ bTf,
                                                  const __bf16* __restrict__ WTf,
                                                  float* __restrict__ out) {
    __shared__ __align__(16) __bf16 Gs[64 * 1024];   // 128 KB

    const int t = threadIdx.x;
    const int w = t >> 6;              // 0..15
    const int l = t & 63;
    const int lane = l & 31;
    const int kh = l >> 5;
    const int r0 = blockIdx.x * 8;
    const int t0 = blockIdx.y * 8;

    // ---------------- Phase A ----------------
    const int rg = w >> 2;             // 0..3
    const int tg = w & 3;              // 0..3

    f32x16 acc[2][2];
#pragma unroll
    for (int i = 0; i < 2; ++i)
#pragma unroll
        for (int j = 0; j < 2; ++j)
#pragma unroll
            for (int q = 0; q < 16; ++q) acc[i][j][q] = 0.f;

    const bf16x8* ap0 = (const bf16x8*)aTf + ((size_t)(r0 + 2 * rg + 0) * 512 + kh * 32 + lane);
    const bf16x8* ap1 = (const bf16x8*)aTf + ((size_t)(r0 + 2 * rg + 1) * 512 + kh * 32 + lane);
    const bf16x8* bp0 = (const bf16x8*)bTf + ((size_t)(t0 + 2 * tg + 0) * 512 + kh * 32 + lane);
    const bf16x8* bp1 = (const bf16x8*)bTf + ((size_t)(t0 + 2 * tg + 1) * 512 + kh * 32 + lane);

    bf16x8 A0[2], B0[2], A1[2], B1[2];
#define LDA(Aa, Bb, ks) do { \
    Aa[0] = ap0[(ks) * 64]; Aa[1] = ap1[(ks) * 64]; \
    Bb[0] = bp0[(ks) * 64]; Bb[1] = bp1[(ks) * 64]; } while (0)
#define PH_A(Aa, Bb) do { \
    __builtin_amdgcn_s_setprio(1); \
    acc[0][0] = MFMA(Aa[0], Bb[0], acc[0][0], 0, 0, 0); \
    acc[0][1] = MFMA(Aa[0], Bb[1], acc[0][1], 0, 0, 0); \
    acc[1][0] = MFMA(Aa[1], Bb[0], acc[1][0], 0, 0, 0); \
    acc[1][1] = MFMA(Aa[1], Bb[1], acc[1][1], 0, 0, 0); \
    __builtin_amdgcn_s_setprio(0); } while (0)

    LDA(A0, B0, 0);
#pragma unroll
    for (int ks = 0; ks < 8; ks += 2) {
        LDA(A1, B1, ks + 1);
        PH_A(A0, B0);
        LDA(A0, B0, (ks + 2) & 7);
        PH_A(A1, B1);
    }

    // G -> LDS, row p = rlocal*8 + tlocal (2048 B), chunk swizzle
#pragma unroll
    for (int i = 0; i < 2; ++i) {
#pragma unroll
        for (int j = 0; j < 2; ++j) {
            int p = (2 * rg + i) * 8 + 2 * tg + j;
            unsigned prow = (unsigned)p * 2048;
#pragma unroll
            for (int q = 0; q < 4; ++q) {
                int Lc = lane * 4 + q;
                int P = Lc ^ (p & 15) ^ (lane & 7);
                *(bf16x4*)((char*)Gs + prow + (unsigned)P * 16 + kh * 8) =
                    cvt4(acc[i][j][4 * q + 0], acc[i][j][4 * q + 1],
                         acc[i][j][4 * q + 2], acc[i][j][4 * q + 3]);
            }
        }
    }
    __syncthreads();

    // ---------------- Phase B ----------------
    const int kq = w >> 2;             // K-quarter 0..3
    const int mt = (w >> 1) & 1;       // M-tile
    const int ng = w & 1;              // cz pair-group
    const int czl0 = ng * 64 + lane;
    const int czl1 = czl0 + 32;
    const bf16x8* wb0 = (const bf16x8*)WTf + ((size_t)kh * 128 + czl0);
    const bf16x8* wb1 = (const bf16x8*)WTf + ((size_t)kh * 128 + czl1);
    const unsigned prowG = (unsigned)(mt * 32 + lane) * 2048;
    const int p15 = lane & 15;

    f32x16 o0, o1;
#pragma unroll
    for (int q = 0; q < 16; ++q) { o0[q] = 0.f; o1[q] = 0.f; }

    bf16x8 Wa0, Wa1, Ga, Wb0_, Wb1_, Gb;
#define LDB(W0v, W1v, Gv, kk) do { \
    W0v = wb0[(size_t)(kk) * 256]; \
    W1v = wb1[(size_t)(kk) * 256]; \
    int Lr = (kk) * 2 + kh; \
    int P = Lr ^ p15 ^ ((Lr >> 2) & 7); \
    Gv = *(const bf16x8*)((const char*)Gs + prowG + (unsigned)P * 16); } while (0)
#define PHB(W0v, W1v, Gv) do { \
    __builtin_amdgcn_s_setprio(1); \
    o0 = MFMA(Gv, W0v, o0, 0, 0, 0); \
    o1 = MFMA(Gv, W1v, o1, 0, 0, 0); \
    __builtin_amdgcn_s_setprio(0); } while (0)

    LDB(Wa0, Wa1, Ga, kq * 16);
#pragma unroll
    for (int j = 0; j < 16; j += 2) {
        LDB(Wb0_, Wb1_, Gb, kq * 16 + ((j + 1) & 15));
        PHB(Wa0, Wa1, Ga);
        LDB(Wa0, Wa1, Ga, kq * 16 + ((j + 2) & 15));
        PHB(Wb0_, Wb1_, Gb);
    }
    __syncthreads();   // all G reads done; region reusable

    if (kq > 0) {
        char* pr = (char*)Gs + (size_t)((kq - 1) * 4 + mt * 2 + ng) * 8192;
#pragma unroll
        for (int oi = 0; oi < 2; ++oi) {
            const f32x16& ov = oi ? o1 : o0;
#pragma unroll
            for (int pc = 0; pc < 4; ++pc) {
                f32x4 v;
                v[0] = ov[4 * pc + 0]; v[1] = ov[4 * pc + 1];
                v[2] = ov[4 * pc + 2]; v[3] = ov[4 * pc + 3];
                *(f32x4*)(pr + ((oi * 4 + pc) * 64 + l) * 16) = v;
            }
        }
    }
    __syncthreads();

    if (kq == 0) {
#pragma unroll
        for (int kq2 = 1; kq2 < 4; ++kq2) {
            const char* pr = (const char*)Gs + (size_t)((kq2 - 1) * 4 + mt * 2 + ng) * 8192;
#pragma unroll
            for (int pc = 0; pc < 4; ++pc) {
                f32x4 v0 = *(const f32x4*)(pr + ((pc) * 64 + l) * 16);
                f32x4 v1 = *(const f32x4*)(pr + ((4 + pc) * 64 + l) * 16);
                o0[4 * pc + 0] += v0[0]; o0[4 * pc + 1] += v0[1];
                o0[4 * pc + 2] += v0[2]; o0[4 * pc + 3] += v0[3];
                o1[4 * pc + 0] += v1[0]; o1[4 * pc + 1] += v1[1];
                o1[4 * pc + 2] += v1[2]; o1[4 * pc + 3] += v1[3];
            }
        }
#pragma unroll
        for (int reg = 0; reg < 16; ++reg) {
            int pl = mt * 32 + (reg & 3) + 8 * (reg >> 2) + 4 * kh;
            int pr2 = pl >> 3, pt = pl & 7;
            out[((size_t)(r0 + pr2) * 256 + (t0 + pt)) * 128 + czl0] = o0[reg];
            out[((size_t)(r0 + pr2) * 256 + (t0 + pt)) * 128 + czl1] = o1[reg];
        }
    }
}

extern "C" void kernel_launch(void* const* d_in, const int* in_sizes, int n_in,
                              void* d_out, int out_size, void* d_ws, size_t ws_size,
                              hipStream_t stream) {
    const float* msa = (const float*)d_in[0];
    const float* left = (const float*)d_in[1];
    const float* right = (const float*)d_in[2];
    const float* W = (const float*)d_in[3];

    __bf16* aTf = (__bf16*)d_ws;                        // 2 MB
    __bf16* bTf = aTf + (size_t)R * 4096;               // 2 MB
    __bf16* WTf = bTf + (size_t)R * 4096;               // 256 KB
    __bf16* WLRT = WTf + (size_t)128 * 1024;            // 32 KB
    float* outp = (float*)d_out;

    k_wt<<<512, 256, 0, stream>>>(W, WTf);
    k_wlr<<<64, 256, 0, stream>>>(left, right, WLRT);
    k_proj<<<dim3(256, 2), 512, 0, stream>>>(msa, WLRT, aTf, bTf);
    k_main<<<dim3(32, 32), 1024, 0, stream>>>(aTf, bTf, WTf, outp);
}

// Round 9
// 64.159 us; speedup vs baseline: 1.0436x; 1.0436x over previous
//
#include <hip/hip_runtime.h>

typedef __bf16 bf16x8 __attribute__((ext_vector_type(8)));
typedef __bf16 bf16x4 __attribute__((ext_vector_type(4)));
typedef float f32x16 __attribute__((ext_vector_type(16)));
typedef float f32x4 __attribute__((ext_vector_type(4)));

constexpr int S = 128, R = 256, CM = 256, C = 32, CZ = 128;

#define MFMA __builtin_amdgcn_mfma_f32_32x32x16_bf16

__device__ __forceinline__ bf16x4 cvt4(float a, float b, float c, float d) {
    bf16x4 r;
    r[0] = (__bf16)a; r[1] = (__bf16)b; r[2] = (__bf16)c; r[3] = (__bf16)d;
    return r;
}

// K0: merged prep. blocks 0..511: WTf[((k>>3)*128+cz)*8+(k&7)] = bf16(W[(c*32+e)*128+cz]);
// blocks 512..575: WLRT[c][m] from left/right.
__global__ __launch_bounds__(256) void k_prep(const float* __restrict__ W,
                                              const float* __restrict__ Lp,
                                              const float* __restrict__ Rp,
                                              __bf16* __restrict__ WTf,
                                              __bf16* __restrict__ WLRT) {
    int b = blockIdx.x;
    if (b < 512) {
        int g = b * 256 + threadIdx.x;
        int cz = g & 127;
        int k = g >> 7;
        int e = k >> 5, c = k & 31;
        float v = W[(size_t)(c * 32 + e) * 128 + cz];
        WTf[((size_t)(k >> 3) * 128 + cz) * 8 + (k & 7)] = (__bf16)v;
    } else {
        int c = b - 512;
        int m = threadIdx.x;
        const float* src = (c < 32) ? Lp : Rp;
        WLRT[(size_t)c * 256 + m] = (__bf16)src[(size_t)m * 32 + (c & 31)];
    }
}

// K1: block (r, s-half=64 rows). 512 thr / 8 waves = (ksh x sd x mi); K(m)-split
// halves + 2-way LDS reduction. Writes fragment-packed aTf/bTf[r][ks][khf][c][8s].
__global__ __launch_bounds__(512) void k_proj(const float* __restrict__ msa,
                                              const __bf16* __restrict__ WLRT,
                                              __bf16* __restrict__ aTf,
                                              __bf16* __restrict__ bTf) {
    __shared__ __align__(16) __bf16 As[64 * 256];       // 32 KB
    __shared__ __align__(16) char Pp[4 * 4096];         // 16 KB partials
    const int r = blockIdx.x;
    const int sh = blockIdx.y;
    const int t = threadIdx.x;

#pragma unroll
    for (int it = 0; it < 8; ++it) {
        int idx = it * 512 + t;
        int row = idx >> 6;
        int cg = idx & 63;
        float4 v = *(const float4*)&msa[((size_t)(sh * 64 + row) * R + r) * CM + cg * 4];
        bf16x4 h = cvt4(v.x, v.y, v.z, v.w);
        int P = (cg >> 1) ^ (row & 15);
        *(bf16x4*)((char*)As + row * 512 + P * 16 + (cg & 1) * 8) = h;
    }
    __syncthreads();

    const int w = t >> 6;
    const int l = t & 63;
    const int l31 = t & 31;
    const int kh = (t >> 5) & 1;
    const int ksh = w >> 2;
    const int sd = (w >> 1) & 1;
    const int mi = w & 1;

    f32x16 acc;
#pragma unroll
    for (int q = 0; q < 16; ++q) acc[q] = 0.f;

    const bf16x8* wb = (const bf16x8*)&WLRT[(size_t)(sd * 32 + l31) * 256 + 8 * kh];
    const int srow = mi * 32 + l31;
    const char* arow = (const char*)As + srow * 512;

    __builtin_amdgcn_s_setprio(1);
#pragma unroll
    for (int j = 0; j < 8; ++j) {
        int ks = ksh * 8 + j;
        int P = (2 * ks + kh) ^ (srow & 15);
        bf16x8 af = *(const bf16x8*)(arow + P * 16);
        acc = MFMA(af, wb[2 * ks], acc, 0, 0, 0);
    }
    __builtin_amdgcn_s_setprio(0);

    char* pbase = Pp + (size_t)(sd * 2 + mi) * 4096;
    if (ksh == 1) {
#pragma unroll
        for (int pc = 0; pc < 4; ++pc) {
            f32x4 v;
            v[0] = acc[4 * pc + 0]; v[1] = acc[4 * pc + 1];
            v[2] = acc[4 * pc + 2]; v[3] = acc[4 * pc + 3];
            *(f32x4*)(pbase + ((pc * 64) + l) * 16) = v;
        }
    }
    __syncthreads();
    if (ksh == 0) {
#pragma unroll
        for (int pc = 0; pc < 4; ++pc) {
            f32x4 v = *(const f32x4*)(pbase + ((pc * 64) + l) * 16);
            acc[4 * pc + 0] += v[0]; acc[4 * pc + 1] += v[1];
            acc[4 * pc + 2] += v[2]; acc[4 * pc + 3] += v[3];
        }
        __bf16* dst = sd ? bTf : aTf;
        const int wg = sh * 2 + mi;
#pragma unroll
        for (int q = 0; q < 4; ++q) {
            size_t base = (size_t)r * 4096 + (size_t)(2 * wg + (q >> 1)) * 512 +
                          (size_t)(q & 1) * 256 + (size_t)l31 * 8 + 4 * kh;
            *(bf16x4*)&dst[base] = cvt4(acc[4 * q + 0], acc[4 * q + 1],
                                        acc[4 * q + 2], acc[4 * q + 3]);
        }
    }
}

// K2: 64 pairs (8r x 8t), 1024 threads / 16 waves, 128 KB LDS.
// Stage: a/b tiles (64+64 KB) -> LDS once (kills 4x VMEM duplication).
// Phase A: wave (rg,tg) 2r x 2t from LDS fragments. barrier -> G overwrites LDS.
// Phase B: wave (kq, ns): both M-tiles x 1 cz-slice over K-quarter; each W
// fragment loaded once per block. 4-way K reduction via dead-G LDS partials.
__global__ __launch_bounds__(1024, 4) void k_main(const __bf16* __restrict__ aTf,
                                                  const __bf16* __restrict__ bTf,
                                                  const __bf16* __restrict__ WTf,
                                                  float* __restrict__ out) {
    __shared__ __align__(16) __bf16 Lds[64 * 1024];   // 128 KB (a/b -> G -> partials)

    const int t = threadIdx.x;
    const int w = t >> 6;              // 0..15
    const int l = t & 63;
    const int lane = l & 31;
    const int kh = l >> 5;
    const int r0 = blockIdx.x * 8;
    const int t0 = blockIdx.y * 8;

    // ---------------- Stage a/b -> LDS (linear, contiguous) ----------------
    {
        const bf16x8* ga = (const bf16x8*)(aTf + (size_t)r0 * 4096);
        const bf16x8* gb = (const bf16x8*)(bTf + (size_t)t0 * 4096);
        bf16x8* ls = (bf16x8*)Lds;
        bf16x8 va[4], vb[4];
#pragma unroll
        for (int i = 0; i < 4; ++i) {
            int idx = i * 1024 + t;
            va[i] = ga[idx];
            vb[i] = gb[idx];
        }
#pragma unroll
        for (int i = 0; i < 4; ++i) {
            int idx = i * 1024 + t;
            ls[idx] = va[i];
            ls[4096 + idx] = vb[i];
        }
    }
    __syncthreads();

    // ---------------- Phase A (operands from LDS) ----------------
    const int rg = w >> 2;
    const int tg = w & 3;

    f32x16 acc[2][2];
#pragma unroll
    for (int i = 0; i < 2; ++i)
#pragma unroll
        for (int j = 0; j < 2; ++j)
#pragma unroll
            for (int q = 0; q < 16; ++q) acc[i][j][q] = 0.f;

    const char* a0p = (const char*)Lds + (2 * rg + 0) * 8192 + kh * 512 + lane * 16;
    const char* a1p = (const char*)Lds + (2 * rg + 1) * 8192 + kh * 512 + lane * 16;
    const char* b0p = (const char*)Lds + 65536 + (2 * tg + 0) * 8192 + kh * 512 + lane * 16;
    const char* b1p = (const char*)Lds + 65536 + (2 * tg + 1) * 8192 + kh * 512 + lane * 16;

    bf16x8 A0[2], B0[2], A1[2], B1[2];
#define LDA(Aa, Bb, ks) do { \
    Aa[0] = *(const bf16x8*)(a0p + (ks) * 1024); \
    Aa[1] = *(const bf16x8*)(a1p + (ks) * 1024); \
    Bb[0] = *(const bf16x8*)(b0p + (ks) * 1024); \
    Bb[1] = *(const bf16x8*)(b1p + (ks) * 1024); } while (0)
#define PH_A(Aa, Bb) do { \
    __builtin_amdgcn_s_setprio(1); \
    acc[0][0] = MFMA(Aa[0], Bb[0], acc[0][0], 0, 0, 0); \
    acc[0][1] = MFMA(Aa[0], Bb[1], acc[0][1], 0, 0, 0); \
    acc[1][0] = MFMA(Aa[1], Bb[0], acc[1][0], 0, 0, 0); \
    acc[1][1] = MFMA(Aa[1], Bb[1], acc[1][1], 0, 0, 0); \
    __builtin_amdgcn_s_setprio(0); } while (0)

    LDA(A0, B0, 0);
#pragma unroll
    for (int ks = 0; ks < 8; ks += 2) {
        LDA(A1, B1, ks + 1);
        PH_A(A0, B0);
        LDA(A0, B0, (ks + 2) & 7);
        PH_A(A1, B1);
    }
    __syncthreads();   // all a/b LDS reads complete; region becomes G

    // ---------------- G -> LDS (swizzled), overwriting a/b ----------------
#pragma unroll
    for (int i = 0; i < 2; ++i) {
#pragma unroll
        for (int j = 0; j < 2; ++j) {
            int p = (2 * rg + i) * 8 + 2 * tg + j;
            unsigned prow = (unsigned)p * 2048;
#pragma unroll
            for (int q = 0; q < 4; ++q) {
                int Lc = lane * 4 + q;
                int P = Lc ^ (p & 15) ^ (lane & 7);
                *(bf16x4*)((char*)Lds + prow + (unsigned)P * 16 + kh * 8) =
                    cvt4(acc[i][j][4 * q + 0], acc[i][j][4 * q + 1],
                         acc[i][j][4 * q + 2], acc[i][j][4 * q + 3]);
            }
        }
    }
    __syncthreads();

    // ---------------- Phase B: (kq, ns), W loaded once per block ----------------
    const int kq = w >> 2;             // K-quarter 0..3
    const int ns = w & 3;              // cz-slice 0..3
    const int czl = ns * 32 + lane;
    const bf16x8* wb = (const bf16x8*)WTf + ((size_t)kh * 128 + czl);
    const unsigned prow0 = (unsigned)lane * 2048;          // M-tile 0 rows
    const unsigned prow1 = (unsigned)(lane + 32) * 2048;   // M-tile 1 rows
    const int p15 = lane & 15;

    f32x16 o0, o1;
#pragma unroll
    for (int q = 0; q < 16; ++q) { o0[q] = 0.f; o1[q] = 0.f; }

    bf16x8 Wa, Ga0, Ga1, Wb_, Gb0, Gb1;
#define LDB(Wv, G0v, G1v, kk) do { \
    Wv = wb[(size_t)(kk) * 256]; \
    int Lr = (kk) * 2 + kh; \
    int P = Lr ^ p15 ^ ((Lr >> 2) & 7); \
    G0v = *(const bf16x8*)((const char*)Lds + prow0 + (unsigned)P * 16); \
    G1v = *(const bf16x8*)((const char*)Lds + prow1 + (unsigned)P * 16); } while (0)
#define PHB(Wv, G0v, G1v) do { \
    __builtin_amdgcn_s_setprio(1); \
    o0 = MFMA(G0v, Wv, o0, 0, 0, 0); \
    o1 = MFMA(G1v, Wv, o1, 0, 0, 0); \
    __builtin_amdgcn_s_setprio(0); } while (0)

    LDB(Wa, Ga0, Ga1, kq * 16);
#pragma unroll
    for (int j = 0; j < 16; j += 2) {
        LDB(Wb_, Gb0, Gb1, kq * 16 + ((j + 1) & 15));
        PHB(Wa, Ga0, Ga1);
        LDB(Wa, Ga0, Ga1, kq * 16 + ((j + 2) & 15));
        PHB(Wb_, Gb0, Gb1);
    }
    __syncthreads();   // all G reads done; region reusable for partials

    if (kq > 0) {
        char* pr = (char*)Lds + (size_t)((kq - 1) * 4 + ns) * 8192;
#pragma unroll
        for (int oi = 0; oi < 2; ++oi) {
            const f32x16& ov = oi ? o1 : o0;
#pragma unroll
            for (int pc = 0; pc < 4; ++pc) {
                f32x4 v;
                v[0] = ov[4 * pc + 0]; v[1] = ov[4 * pc + 1];
                v[2] = ov[4 * pc + 2]; v[3] = ov[4 * pc + 3];
                *(f32x4*)(pr + ((oi * 4 + pc) * 64 + l) * 16) = v;
            }
        }
    }
    __syncthreads();

    if (kq == 0) {
#pragma unroll
        for (int kq2 = 1; kq2 < 4; ++kq2) {
            const char* pr = (const char*)Lds + (size_t)((kq2 - 1) * 4 + ns) * 8192;
#pragma unroll
            for (int pc = 0; pc < 4; ++pc) {
                f32x4 v0 = *(const f32x4*)(pr + ((pc) * 64 + l) * 16);
                f32x4 v1 = *(const f32x4*)(pr + ((4 + pc) * 64 + l) * 16);
                o0[4 * pc + 0] += v0[0]; o0[4 * pc + 1] += v0[1];
                o0[4 * pc + 2] += v0[2]; o0[4 * pc + 3] += v0[3];
                o1[4 * pc + 0] += v1[0]; o1[4 * pc + 1] += v1[1];
                o1[4 * pc + 2] += v1[2]; o1[4 * pc + 3] += v1[3];
            }
        }
#pragma unroll
        for (int reg = 0; reg < 16; ++reg) {
            int base = (reg & 3) + 8 * (reg >> 2) + 4 * kh;
            int pl0 = base;            // M-tile 0
            int pl1 = 32 + base;       // M-tile 1
            out[((size_t)(r0 + (pl0 >> 3)) * 256 + (t0 + (pl0 & 7))) * 128 + czl] = o0[reg];
            out[((size_t)(r0 + (pl1 >> 3)) * 256 + (t0 + (pl1 & 7))) * 128 + czl] = o1[reg];
        }
    }
}

extern "C" void kernel_launch(void* const* d_in, const int* in_sizes, int n_in,
                              void* d_out, int out_size, void* d_ws, size_t ws_size,
                              hipStream_t stream) {
    const float* msa = (const float*)d_in[0];
    const float* left = (const float*)d_in[1];
    const float* right = (const float*)d_in[2];
    const float* W = (const float*)d_in[3];

    __bf16* aTf = (__bf16*)d_ws;                        // 2 MB
    __bf16* bTf = aTf + (size_t)R * 4096;               // 2 MB
    __bf16* WTf = bTf + (size_t)R * 4096;               // 256 KB
    __bf16* WLRT = WTf + (size_t)128 * 1024;            // 32 KB
    float* outp = (float*)d_out;

    k_prep<<<576, 256, 0, stream>>>(W, left, right, WTf, WLRT);
    k_proj<<<dim3(256, 2), 512, 0, stream>>>(msa, WLRT, aTf, bTf);
    k_main<<<dim3(32, 32), 1024, 0, stream>>>(aTf, bTf, WTf, outp);
}

// Round 10
// 59.089 us; speedup vs baseline: 1.1331x; 1.0858x over previous
//
#include <hip/hip_runtime.h>

typedef __bf16 bf16x8 __attribute__((ext_vector_type(8)));
typedef __bf16 bf16x4 __attribute__((ext_vector_type(4)));
typedef float f32x16 __attribute__((ext_vector_type(16)));
typedef float f32x4 __attribute__((ext_vector_type(4)));

constexpr int S = 128, R = 256, CM = 256, C = 32, CZ = 128;

#define MFMA __builtin_amdgcn_mfma_f32_32x32x16_bf16

__device__ __forceinline__ bf16x4 cvt4(float a, float b, float c, float d) {
    bf16x4 r;
    r[0] = (__bf16)a; r[1] = (__bf16)b; r[2] = (__bf16)c; r[3] = (__bf16)d;
    return r;
}

// K0: merged prep. blocks 0..511: WTf[((k>>3)*128+cz)*8+(k&7)] = bf16(W[(c*32+e)*128+cz]);
// blocks 512..575: WLRT[c][m] from left/right.
__global__ __launch_bounds__(256) void k_prep(const float* __restrict__ W,
                                              const float* __restrict__ Lp,
                                              const float* __restrict__ Rp,
                                              __bf16* __restrict__ WTf,
                                              __bf16* __restrict__ WLRT) {
    int b = blockIdx.x;
    if (b < 512) {
        int g = b * 256 + threadIdx.x;
        int cz = g & 127;
        int k = g >> 7;
        int e = k >> 5, c = k & 31;
        float v = W[(size_t)(c * 32 + e) * 128 + cz];
        WTf[((size_t)(k >> 3) * 128 + cz) * 8 + (k & 7)] = (__bf16)v;
    } else {
        int c = b - 512;
        int m = threadIdx.x;
        const float* src = (c < 32) ? Lp : Rp;
        WLRT[(size_t)c * 256 + m] = (__bf16)src[(size_t)m * 32 + (c & 31)];
    }
}

// K1 v3: block (r, s-quarter=32 rows), 256 thr / 4 waves = (ksh x sd).
// K(m)-split halves + 2-way LDS reduction. Writes aTf/bTf[r][ks][khf][c][8s].
__global__ __launch_bounds__(256) void k_proj(const float* __restrict__ msa,
                                              const __bf16* __restrict__ WLRT,
                                              __bf16* __restrict__ aTf,
                                              __bf16* __restrict__ bTf) {
    __shared__ __align__(16) __bf16 As[32 * 256];       // 16 KB
    __shared__ __align__(16) char Pp[2 * 4096];         // 8 KB partials
    const int r = blockIdx.x;
    const int sq = blockIdx.y;                          // 0..3
    const int t = threadIdx.x;

#pragma unroll
    for (int it = 0; it < 8; ++it) {
        int idx = it * 256 + t;
        int row = idx >> 6;            // 0..31
        int cg = idx & 63;
        float4 v = *(const float4*)&msa[((size_t)(sq * 32 + row) * R + r) * CM + cg * 4];
        bf16x4 h = cvt4(v.x, v.y, v.z, v.w);
        int P = (cg >> 1) ^ (row & 15);
        *(bf16x4*)((char*)As + row * 512 + P * 16 + (cg & 1) * 8) = h;
    }
    __syncthreads();

    const int w = t >> 6;
    const int l = t & 63;
    const int l31 = t & 31;
    const int kh = (t >> 5) & 1;
    const int sd = w & 1;              // 0 = left, 1 = right
    const int ksh = w >> 1;            // m-half

    f32x16 acc;
#pragma unroll
    for (int q = 0; q < 16; ++q) acc[q] = 0.f;

    const bf16x8* wb = (const bf16x8*)&WLRT[(size_t)(sd * 32 + l31) * 256 + 8 * kh];
    const char* arow = (const char*)As + l31 * 512;

    __builtin_amdgcn_s_setprio(1);
#pragma unroll
    for (int j = 0; j < 8; ++j) {
        int ks = ksh * 8 + j;
        int P = (2 * ks + kh) ^ (l31 & 15);
        bf16x8 af = *(const bf16x8*)(arow + P * 16);
        acc = MFMA(af, wb[2 * ks], acc, 0, 0, 0);
    }
    __builtin_amdgcn_s_setprio(0);

    char* pbase = Pp + (size_t)sd * 4096;
    if (ksh == 1) {
#pragma unroll
        for (int pc = 0; pc < 4; ++pc) {
            f32x4 v;
            v[0] = acc[4 * pc + 0]; v[1] = acc[4 * pc + 1];
            v[2] = acc[4 * pc + 2]; v[3] = acc[4 * pc + 3];
            *(f32x4*)(pbase + ((pc * 64) + l) * 16) = v;
        }
    }
    __syncthreads();
    if (ksh == 0) {
#pragma unroll
        for (int pc = 0; pc < 4; ++pc) {
            f32x4 v = *(const f32x4*)(pbase + ((pc * 64) + l) * 16);
            acc[4 * pc + 0] += v[0]; acc[4 * pc + 1] += v[1];
            acc[4 * pc + 2] += v[2]; acc[4 * pc + 3] += v[3];
        }
        __bf16* dst = sd ? bTf : aTf;
#pragma unroll
        for (int q = 0; q < 4; ++q) {
            size_t base = (size_t)r * 4096 + (size_t)(2 * sq + (q >> 1)) * 512 +
                          (size_t)(q & 1) * 256 + (size_t)l31 * 8 + 4 * kh;
            *(bf16x4*)&dst[base] = cvt4(acc[4 * q + 0], acc[4 * q + 1],
                                        acc[4 * q + 2], acc[4 * q + 3]);
        }
    }
}

// K2: 64 pairs (8r x 8t), 512 thr / 8 waves, G in 128 KB LDS (r7 skeleton).
// Phase A: wave (rg=w&3, tg=w>>2) -> 2r x 4t, depth-3 unrolled prefetch.
// Phase B: wave (kq=w>>1, ng=w&1): 2 M-tiles x 2 cz-slices over K-quarter,
// depth-5 unrolled prefetch; W loaded exactly once per block.
__global__ __launch_bounds__(512, 2) void k_main(const __bf16* __restrict__ aTf,
                                                 const __bf16* __restrict__ bTf,
                                                 const __bf16* __restrict__ WTf,
                                                 float* __restrict__ out) {
    __shared__ __align__(16) __bf16 Gs[64 * 1024];   // 128 KB

    const int t = threadIdx.x;
    const int w = t >> 6;              // 0..7
    const int l = t & 63;
    const int lane = l & 31;
    const int kh = l >> 5;
    const int r0 = blockIdx.x * 8;
    const int t0 = blockIdx.y * 8;

    // ---------------- Phase A ----------------
    const int rg = w & 3;
    const int tg = w >> 2;

    f32x16 acc[2][4];
#pragma unroll
    for (int i = 0; i < 2; ++i)
#pragma unroll
        for (int j = 0; j < 4; ++j)
#pragma unroll
            for (int q = 0; q < 16; ++q) acc[i][j][q] = 0.f;

    const bf16x8* ap0 = (const bf16x8*)aTf + ((size_t)(r0 + 2 * rg + 0) * 512 + kh * 32 + lane);
    const bf16x8* ap1 = (const bf16x8*)aTf + ((size_t)(r0 + 2 * rg + 1) * 512 + kh * 32 + lane);
    const bf16x8* bp0 = (const bf16x8*)bTf + ((size_t)(t0 + 4 * tg + 0) * 512 + kh * 32 + lane);
    const bf16x8* bp1 = (const bf16x8*)bTf + ((size_t)(t0 + 4 * tg + 1) * 512 + kh * 32 + lane);
    const bf16x8* bp2 = (const bf16x8*)bTf + ((size_t)(t0 + 4 * tg + 2) * 512 + kh * 32 + lane);
    const bf16x8* bp3 = (const bf16x8*)bTf + ((size_t)(t0 + 4 * tg + 3) * 512 + kh * 32 + lane);

    bf16x8 Ap[3][2], Bp[3][4];
#pragma unroll
    for (int s = 0; s < 3; ++s) {
        Ap[s][0] = ap0[s * 64]; Ap[s][1] = ap1[s * 64];
        Bp[s][0] = bp0[s * 64]; Bp[s][1] = bp1[s * 64];
        Bp[s][2] = bp2[s * 64]; Bp[s][3] = bp3[s * 64];
    }
#pragma unroll
    for (int ks = 0; ks < 8; ++ks) {
        const int s = ks % 3;
        __builtin_amdgcn_s_setprio(1);
        acc[0][0] = MFMA(Ap[s][0], Bp[s][0], acc[0][0], 0, 0, 0);
        acc[0][1] = MFMA(Ap[s][0], Bp[s][1], acc[0][1], 0, 0, 0);
        acc[0][2] = MFMA(Ap[s][0], Bp[s][2], acc[0][2], 0, 0, 0);
        acc[0][3] = MFMA(Ap[s][0], Bp[s][3], acc[0][3], 0, 0, 0);
        acc[1][0] = MFMA(Ap[s][1], Bp[s][0], acc[1][0], 0, 0, 0);
        acc[1][1] = MFMA(Ap[s][1], Bp[s][1], acc[1][1], 0, 0, 0);
        acc[1][2] = MFMA(Ap[s][1], Bp[s][2], acc[1][2], 0, 0, 0);
        acc[1][3] = MFMA(Ap[s][1], Bp[s][3], acc[1][3], 0, 0, 0);
        __builtin_amdgcn_s_setprio(0);
        if (ks + 3 < 8) {
            const int kn = ks + 3;
            Ap[s][0] = ap0[kn * 64]; Ap[s][1] = ap1[kn * 64];
            Bp[s][0] = bp0[kn * 64]; Bp[s][1] = bp1[kn * 64];
            Bp[s][2] = bp2[kn * 64]; Bp[s][3] = bp3[kn * 64];
        }
    }

    // G -> LDS, row p = rlocal*8 + tlocal (2048 B), chunk swizzle
#pragma unroll
    for (int i = 0; i < 2; ++i) {
#pragma unroll
        for (int j = 0; j < 4; ++j) {
            int p = (2 * rg + i) * 8 + 4 * tg + j;
            unsigned prow = (unsigned)p * 2048;
#pragma unroll
            for (int q = 0; q < 4; ++q) {
                int Lc = lane * 4 + q;
                int P = Lc ^ (p & 15) ^ (lane & 7);
                *(bf16x4*)((char*)Gs + prow + (unsigned)P * 16 + kh * 8) =
                    cvt4(acc[i][j][4 * q + 0], acc[i][j][4 * q + 1],
                         acc[i][j][4 * q + 2], acc[i][j][4 * q + 3]);
            }
        }
    }
    __syncthreads();

    // ---------------- Phase B ----------------
    const int kq = w >> 1;             // K-quarter 0..3
    const int ng = w & 1;              // cz pair-group
    const int czl0 = ng * 64 + lane;
    const int czl1 = czl0 + 32;
    const bf16x8* wb0 = (const bf16x8*)WTf + ((size_t)kh * 128 + czl0);
    const bf16x8* wb1 = (const bf16x8*)WTf + ((size_t)kh * 128 + czl1);
    const unsigned prow0 = (unsigned)lane * 2048;
    const unsigned prow1 = (unsigned)(lane + 32) * 2048;
    const int p15 = lane & 15;

    f32x16 o00, o01, o10, o11;
#pragma unroll
    for (int q = 0; q < 16; ++q) { o00[q] = 0.f; o01[q] = 0.f; o10[q] = 0.f; o11[q] = 0.f; }

    bf16x8 Wp[5][2], Gp[5][2];
#pragma unroll
    for (int s = 0; s < 5; ++s) {
        const int kk = kq * 16 + s;
        Wp[s][0] = wb0[(size_t)kk * 256];
        Wp[s][1] = wb1[(size_t)kk * 256];
        int Lr = kk * 2 + kh;
        int P = Lr ^ p15 ^ ((Lr >> 2) & 7);
        Gp[s][0] = *(const bf16x8*)((const char*)Gs + prow0 + (unsigned)P * 16);
        Gp[s][1] = *(const bf16x8*)((const char*)Gs + prow1 + (unsigned)P * 16);
    }
#pragma unroll
    for (int j = 0; j < 16; ++j) {
        const int s = j % 5;
        __builtin_amdgcn_s_setprio(1);
        o00 = MFMA(Gp[s][0], Wp[s][0], o00, 0, 0, 0);
        o01 = MFMA(Gp[s][0], Wp[s][1], o01, 0, 0, 0);
        o10 = MFMA(Gp[s][1], Wp[s][0], o10, 0, 0, 0);
        o11 = MFMA(Gp[s][1], Wp[s][1], o11, 0, 0, 0);
        __builtin_amdgcn_s_setprio(0);
        if (j + 5 < 16) {
            const int kk = kq * 16 + j + 5;
            Wp[s][0] = wb0[(size_t)kk * 256];
            Wp[s][1] = wb1[(size_t)kk * 256];
            int Lr = kk * 2 + kh;
            int P = Lr ^ p15 ^ ((Lr >> 2) & 7);
            Gp[s][0] = *(const bf16x8*)((const char*)Gs + prow0 + (unsigned)P * 16);
            Gp[s][1] = *(const bf16x8*)((const char*)Gs + prow1 + (unsigned)P * 16);
        }
    }
    __syncthreads();   // all G reads done; region reusable for partials

    // partials: region w*16KB, layout [s2][piece][l] x 16B, s2 = (M,slice)
    {
        char* pr = (char*)Gs + (size_t)w * 16384;
        const f32x16* os[4] = {&o00, &o01, &o10, &o11};
#pragma unroll
        for (int s2 = 0; s2 < 4; ++s2) {
#pragma unroll
            for (int pc = 0; pc < 4; ++pc) {
                f32x4 v;
                v[0] = (*os[s2])[4 * pc + 0]; v[1] = (*os[s2])[4 * pc + 1];
                v[2] = (*os[s2])[4 * pc + 2]; v[3] = (*os[s2])[4 * pc + 3];
                *(f32x4*)(pr + ((s2 * 4 + pc) * 64 + l) * 16) = v;
            }
        }
    }
    __syncthreads();

    // reduce over K-quarters: wave (ngx=w>>2, mix=(w>>1)&1, nix=w&1)
    {
        const int ngx = w >> 2;
        const int mix = (w >> 1) & 1;
        const int nix = w & 1;
        const int s2 = mix * 2 + nix;
        f32x16 sm;
#pragma unroll
        for (int q = 0; q < 16; ++q) sm[q] = 0.f;
#pragma unroll
        for (int kq2 = 0; kq2 < 4; ++kq2) {
            const char* pr = (const char*)Gs + (size_t)(kq2 * 2 + ngx) * 16384;
#pragma unroll
            for (int pc = 0; pc < 4; ++pc) {
                f32x4 v = *(const f32x4*)(pr + ((s2 * 4 + pc) * 64 + l) * 16);
                sm[4 * pc + 0] += v[0]; sm[4 * pc + 1] += v[1];
                sm[4 * pc + 2] += v[2]; sm[4 * pc + 3] += v[3];
            }
        }
        const int czl = ngx * 64 + nix * 32 + (l & 31);
        const int khx = l >> 5;
#pragma unroll
        for (int reg = 0; reg < 16; ++reg) {
            int pl = mix * 32 + (reg & 3) + 8 * (reg >> 2) + 4 * khx;
            int prr = pl >> 3, ptt = pl & 7;
            out[((size_t)(r0 + prr) * 256 + (t0 + ptt)) * 128 + czl] = sm[reg];
        }
    }
}

extern "C" void kernel_launch(void* const* d_in, const int* in_sizes, int n_in,
                              void* d_out, int out_size, void* d_ws, size_t ws_size,
                              hipStream_t stream) {
    const float* msa = (const float*)d_in[0];
    const float* left = (const float*)d_in[1];
    const float* right = (const float*)d_in[2];
    const float* W = (const float*)d_in[3];

    __bf16* aTf = (__bf16*)d_ws;                        // 2 MB
    __bf16* bTf = aTf + (size_t)R * 4096;               // 2 MB
    __bf16* WTf = bTf + (size_t)R * 4096;               // 256 KB
    __bf16* WLRT = WTf + (size_t)128 * 1024;            // 32 KB
    float* outp = (float*)d_out;

    k_prep<<<576, 256, 0, stream>>>(W, left, right, WTf, WLRT);
    k_proj<<<dim3(256, 4), 256, 0, stream>>>(msa, WLRT, aTf, bTf);
    k_main<<<dim3(32, 32), 512, 0, stream>>>(aTf, bTf, WTf, outp);
}